// Round 1
// 374.354 us; speedup vs baseline: 1.1391x; 1.1391x over previous
//
#include <hip/hip_runtime.h>

#define NCAT 32
#define NTOK 512
#define HID  512
#define EMB  1024
#define DSTATE 192

// ws layout:
//   [0,128)        int cnt[32]
//   [128,136)      int nW[2]        (nW[0]=layer1 chunks of 8, nW[1]=layer2 chunks of 16)
//   [256,640)      int work1[96]    entries: cat | (chunk<<8)   (max sum ceil(n/8) = 92)
//   [640,896)      int work2[64]    (max sum ceil(n/16) = 62)
//   [1024,66560)   int toklist[32][512]
//   [66560,+4MiB)  float H[512 tok][4 mod][512]

__global__ __launch_bounds__(512) void bucket_kernel(
    const int* __restrict__ ids, int* __restrict__ cnt, int* __restrict__ nW,
    int* __restrict__ work1, int* __restrict__ work2, int* __restrict__ toklist)
{
    __shared__ int scnt[NCAT];
    const int tid = threadIdx.x;
    if (tid < NCAT) scnt[tid] = 0;
    __syncthreads();
    const int c = ids[tid];                       // 512 threads == 512 tokens
    const int pos = atomicAdd(&scnt[c], 1);       // LDS atomic: cheap
    toklist[c * NTOK + pos] = tid;
    __syncthreads();
    if (tid == 0) {
        int n1 = 0, n2 = 0;
        for (int cc = 0; cc < NCAT; ++cc) {
            const int n = scnt[cc];
            cnt[cc] = n;
            for (int ch = 0; ch * 8 < n; ++ch)  work1[n1++] = cc | (ch << 8);
            for (int ch = 0; ch * 16 < n; ++ch) work2[n2++] = cc | (ch << 8);
        }
        nW[0] = n1; nW[1] = n2;
    }
}

// grid (96 slots, 4 mod, 2 colhalf), 256 threads. 8 tokens/block zero-padded,
// thread owns hid col (z*256 + tid).
__global__ __launch_bounds__(256, 4) void layer1_kernel(
    const float* __restrict__ state,
    const int* __restrict__ cnt, const int* __restrict__ toklist,
    const int* __restrict__ nW, const int* __restrict__ work1,
    const float* __restrict__ W1_0, const float* __restrict__ W1_1,
    const float* __restrict__ W1_2, const float* __restrict__ W1_3,
    const float* __restrict__ b1_0, const float* __restrict__ b1_1,
    const float* __restrict__ b1_2, const float* __restrict__ b1_3,
    float* __restrict__ H)
{
    const int slot = blockIdx.x, mod = blockIdx.y;
    if (slot >= nW[0]) return;
    const int ent = work1[slot];
    const int cat = ent & 255, chunk = ent >> 8;
    const int nC = cnt[cat];
    const int start = chunk * 8;
    int nThis = nC - start;
    if (nThis > 8) nThis = 8;
    const int tid = threadIdx.x;
    const int col = blockIdx.z * 256 + tid;

    const int L   = (mod < 2) ? 64 : 32;
    const int lf4 = L >> 2;
    const int lsh = (mod < 2) ? 4 : 3;
    const int off = (mod == 0) ? 0 : (mod == 1) ? 64 : (mod == 2) ? 128 : 160;

    __shared__ float sX[8 * 64];
    __shared__ int sTok[8];
    if (tid < 8) sTok[tid] = (tid < nThis) ? toklist[cat * NTOK + start + tid] : 0;
    __syncthreads();

    if (tid < (8 << lsh)) {                        // 8*lf4 float4s, one per thread
        const int t = tid >> lsh, e = tid & (lf4 - 1);
        float4 v = make_float4(0.f, 0.f, 0.f, 0.f);
        if (t < nThis)
            v = ((const float4*)(state + sTok[t] * DSTATE + off))[e];
        ((float4*)sX)[t * lf4 + e] = v;
    }
    __syncthreads();

    const float* W1 = (mod == 0) ? W1_0 : (mod == 1) ? W1_1 : (mod == 2) ? W1_2 : W1_3;
    const float* b1 = (mod == 0) ? b1_0 : (mod == 1) ? b1_1 : (mod == 2) ? b1_2 : b1_3;
    const float* Wcol = W1 + cat * L * HID + col;

    float acc[8];
#pragma unroll
    for (int t = 0; t < 8; ++t) acc[t] = 0.f;

#pragma unroll 4
    for (int k4 = 0; k4 < lf4; ++k4) {
        const float* p = Wcol + (k4 * 4) * HID;
        const float w0 = p[0];
        const float w1 = p[HID];
        const float w2 = p[2 * HID];
        const float w3 = p[3 * HID];
#pragma unroll
        for (int t = 0; t < 8; ++t) {
            const float4 x4 = ((const float4*)sX)[t * lf4 + k4];
            acc[t] += x4.x * w0 + x4.y * w1 + x4.z * w2 + x4.w * w3;
        }
    }

    const float b = b1[cat * HID + col];
#pragma unroll
    for (int t = 0; t < 8; ++t) {
        if (t >= nThis) break;
        float h = acc[t] + b;
        H[(sTok[t] * 4 + mod) * HID + col] = h > 0.f ? h : 0.f;
    }
}

// grid (64 slots, 4 mod, 4 colquarter), 256 threads. 16 tokens/block zero-padded,
// full K=512 (no atomics), thread owns col (z*256 + tid).
__global__ __launch_bounds__(256, 4) void layer2_kernel(
    const int* __restrict__ cnt, const int* __restrict__ toklist,
    const int* __restrict__ nW, const int* __restrict__ work2,
    const float* __restrict__ H,
    const float* __restrict__ W2_0, const float* __restrict__ W2_1,
    const float* __restrict__ W2_2, const float* __restrict__ W2_3,
    const float* __restrict__ b2_0, const float* __restrict__ b2_1,
    const float* __restrict__ b2_2, const float* __restrict__ b2_3,
    const float* __restrict__ te_0, const float* __restrict__ te_1,
    const float* __restrict__ te_2, const float* __restrict__ te_3,
    float* __restrict__ out)
{
    const int slot = blockIdx.x, mod = blockIdx.y;
    if (slot >= nW[1]) return;
    const int ent = work2[slot];
    const int cat = ent & 255, chunk = ent >> 8;
    const int nC = cnt[cat];
    const int start = chunk * 16;
    int nThis = nC - start;
    if (nThis > 16) nThis = 16;
    const int tid = threadIdx.x;
    const int col = blockIdx.z * 256 + tid;

    __shared__ float sH[16 * 512];             // 32 KiB, [t][k] zero-padded
    __shared__ int sTok[16];
    if (tid < 16) sTok[tid] = (tid < nThis) ? toklist[cat * NTOK + start + tid] : 0;
    __syncthreads();

    for (int idx = tid; idx < 16 * 128; idx += 256) {   // 2048 float4s
        const int t = idx >> 7, e4 = idx & 127;
        float4 v = make_float4(0.f, 0.f, 0.f, 0.f);
        if (t < nThis)
            v = ((const float4*)(H + (sTok[t] * 4 + mod) * HID))[e4];
        ((float4*)sH)[idx] = v;
    }
    __syncthreads();

    const float* W2 = (mod == 0) ? W2_0 : (mod == 1) ? W2_1 : (mod == 2) ? W2_2 : W2_3;
    const float* b2 = (mod == 0) ? b2_0 : (mod == 1) ? b2_1 : (mod == 2) ? b2_2 : b2_3;
    const float* te = (mod == 0) ? te_0 : (mod == 1) ? te_1 : (mod == 2) ? te_2 : te_3;

    const float* Wcol = W2 + cat * (HID * EMB) + col;

    float acc[16];
#pragma unroll
    for (int t = 0; t < 16; ++t) acc[t] = 0.f;

#pragma unroll 4
    for (int k4 = 0; k4 < 128; ++k4) {
        const float* p = Wcol + (k4 * 4) * EMB;
        const float w0 = p[0];
        const float w1 = p[EMB];
        const float w2 = p[2 * EMB];
        const float w3 = p[3 * EMB];
#pragma unroll
        for (int t = 0; t < 16; ++t) {
            const float4 h4 = ((const float4*)sH)[t * 128 + k4];
            acc[t] += h4.x * w0 + h4.y * w1 + h4.z * w2 + h4.w * w3;
        }
    }

    const float b = b2[cat * EMB + col] + te[col];
#pragma unroll
    for (int t = 0; t < 16; ++t) {
        if (t >= nThis) break;
        out[(sTok[t] * 4 + mod) * EMB + col] = acc[t] + b;
    }
}

extern "C" void kernel_launch(void* const* d_in, const int* in_sizes, int n_in,
                              void* d_out, int out_size, void* d_ws, size_t ws_size,
                              hipStream_t stream) {
    const float* state = (const float*)d_in[0];
    const int*   ids   = (const int*)d_in[1];
    const float *W1[4], *b1[4], *W2[4], *b2[4], *te[4];
    for (int m = 0; m < 4; ++m) {
        W1[m] = (const float*)d_in[2 + 5 * m + 0];
        b1[m] = (const float*)d_in[2 + 5 * m + 1];
        W2[m] = (const float*)d_in[2 + 5 * m + 2];
        b2[m] = (const float*)d_in[2 + 5 * m + 3];
        te[m] = (const float*)d_in[2 + 5 * m + 4];
    }
    char* ws = (char*)d_ws;
    int*   cnt     = (int*)ws;
    int*   nW      = (int*)(ws + 128);
    int*   work1   = (int*)(ws + 256);
    int*   work2   = (int*)(ws + 640);
    int*   toklist = (int*)(ws + 1024);
    float* H       = (float*)(ws + 66560);
    float* out     = (float*)d_out;

    bucket_kernel<<<1, 512, 0, stream>>>(ids, cnt, nW, work1, work2, toklist);
    layer1_kernel<<<dim3(96, 4, 2), 256, 0, stream>>>(
        state, cnt, toklist, nW, work1,
        W1[0], W1[1], W1[2], W1[3],
        b1[0], b1[1], b1[2], b1[3], H);
    layer2_kernel<<<dim3(64, 4, 4), 256, 0, stream>>>(
        cnt, toklist, nW, work2, H,
        W2[0], W2[1], W2[2], W2[3],
        b2[0], b2[1], b2[2], b2[3],
        te[0], te[1], te[2], te[3], out);
}

// Round 2
// 373.367 us; speedup vs baseline: 1.1421x; 1.0026x over previous
//
#include <hip/hip_runtime.h>

#define NCAT 32
#define NTOK 512
#define HID  512
#define EMB  1024
#define DSTATE 192

// ws layout:
//   [0,128)        int cnt[32]
//   [128,136)      int nW[2]        (nW[0]=layer1 chunks of 8, nW[1]=layer2 chunks of 8)
//   [256,640)      int work1[96]    entries: cat | (chunk<<8)   (max sum ceil(n/8) = 95)
//   [640,1024)     int work2[96]
//   [1024,66560)   int toklist[32][512]
//   [66560,+4MiB)  float H[512 tok][4 mod][512]

__global__ __launch_bounds__(512) void bucket_kernel(
    const int* __restrict__ ids, int* __restrict__ cnt, int* __restrict__ nW,
    int* __restrict__ work1, int* __restrict__ work2, int* __restrict__ toklist)
{
    __shared__ int scnt[NCAT];
    const int tid = threadIdx.x;
    if (tid < NCAT) scnt[tid] = 0;
    __syncthreads();
    const int c = ids[tid];                       // 512 threads == 512 tokens
    const int pos = atomicAdd(&scnt[c], 1);       // LDS atomic: cheap
    toklist[c * NTOK + pos] = tid;
    __syncthreads();
    if (tid == 0) {
        int n1 = 0, n2 = 0;
        for (int cc = 0; cc < NCAT; ++cc) {
            const int n = scnt[cc];
            cnt[cc] = n;
            for (int ch = 0; ch * 8 < n; ++ch) work1[n1++] = cc | (ch << 8);
            for (int ch = 0; ch * 8 < n; ++ch) work2[n2++] = cc | (ch << 8);
        }
        nW[0] = n1; nW[1] = n2;
    }
}

// Inner k-loop for layer1, LF4 = L/4 known at compile time.
template <int LF4>
__device__ __forceinline__ void l1_kloop(
    const float* __restrict__ Wcol, const float* __restrict__ sX,
    float4* __restrict__ acc)
{
#pragma unroll 4
    for (int k4 = 0; k4 < LF4; ++k4) {
        const float* p = Wcol + (k4 * 4) * HID;
        const float4 w0 = *(const float4*)(p);
        const float4 w1 = *(const float4*)(p + HID);
        const float4 w2 = *(const float4*)(p + 2 * HID);
        const float4 w3 = *(const float4*)(p + 3 * HID);
#pragma unroll
        for (int t = 0; t < 8; ++t) {
            const float4 x4 = ((const float4*)sX)[t * LF4 + k4];
            acc[t].x += x4.x * w0.x + x4.y * w1.x + x4.z * w2.x + x4.w * w3.x;
            acc[t].y += x4.x * w0.y + x4.y * w1.y + x4.z * w2.y + x4.w * w3.y;
            acc[t].z += x4.x * w0.z + x4.y * w1.z + x4.z * w2.z + x4.w * w3.z;
            acc[t].w += x4.x * w0.w + x4.y * w1.w + x4.z * w2.w + x4.w * w3.w;
        }
    }
}

// grid (96 slots, 4 mod), 128 threads. 8 tokens/block zero-padded,
// thread owns 4 hid cols [4*tid, 4*tid+4).
__global__ __launch_bounds__(128, 2) void layer1_kernel(
    const float* __restrict__ state,
    const int* __restrict__ cnt, const int* __restrict__ toklist,
    const int* __restrict__ nW, const int* __restrict__ work1,
    const float* __restrict__ W1_0, const float* __restrict__ W1_1,
    const float* __restrict__ W1_2, const float* __restrict__ W1_3,
    const float* __restrict__ b1_0, const float* __restrict__ b1_1,
    const float* __restrict__ b1_2, const float* __restrict__ b1_3,
    float* __restrict__ H)
{
    const int slot = blockIdx.x, mod = blockIdx.y;
    if (slot >= nW[0]) return;
    const int ent = work1[slot];
    const int cat = ent & 255, chunk = ent >> 8;
    const int nC = cnt[cat];
    const int start = chunk * 8;
    int nThis = nC - start;
    if (nThis > 8) nThis = 8;
    const int tid = threadIdx.x;
    const int col = 4 * tid;                       // 128 threads x 4 = 512 cols

    const int L    = (mod < 2) ? 64 : 32;
    const int lsh  = (mod < 2) ? 4 : 3;            // log2(L/4)
    const int lf4  = 1 << lsh;
    const int off  = (mod == 0) ? 0 : (mod == 1) ? 64 : (mod == 2) ? 128 : 160;

    __shared__ float sX[8 * 64];
    __shared__ int sTok[8];
    if (tid < 8) sTok[tid] = (tid < nThis) ? toklist[cat * NTOK + start + tid] : 0;
    __syncthreads();

    if (tid < (8 << lsh)) {                        // 8*lf4 float4s, one per thread
        const int t = tid >> lsh, e = tid & (lf4 - 1);
        float4 v = make_float4(0.f, 0.f, 0.f, 0.f);
        if (t < nThis)
            v = ((const float4*)(state + sTok[t] * DSTATE + off))[e];
        ((float4*)sX)[t * lf4 + e] = v;
    }
    __syncthreads();

    const float* W1 = (mod == 0) ? W1_0 : (mod == 1) ? W1_1 : (mod == 2) ? W1_2 : W1_3;
    const float* b1 = (mod == 0) ? b1_0 : (mod == 1) ? b1_1 : (mod == 2) ? b1_2 : b1_3;
    const float* Wcol = W1 + cat * L * HID + col;

    float4 acc[8];
#pragma unroll
    for (int t = 0; t < 8; ++t) acc[t] = make_float4(0.f, 0.f, 0.f, 0.f);

    if (mod < 2) l1_kloop<16>(Wcol, sX, acc);
    else         l1_kloop<8>(Wcol, sX, acc);

    const float4 b = *(const float4*)(b1 + cat * HID + col);
#pragma unroll
    for (int t = 0; t < 8; ++t) {
        if (t >= nThis) break;
        float4 h;
        h.x = acc[t].x + b.x; h.x = h.x > 0.f ? h.x : 0.f;
        h.y = acc[t].y + b.y; h.y = h.y > 0.f ? h.y : 0.f;
        h.z = acc[t].z + b.z; h.z = h.z > 0.f ? h.z : 0.f;
        h.w = acc[t].w + b.w; h.w = h.w > 0.f ? h.w : 0.f;
        *(float4*)(H + (sTok[t] * 4 + mod) * HID + col) = h;
    }
}

// grid (96 slots, 4 mod), 256 threads. 8 tokens/block zero-padded,
// thread owns 4 emb cols [4*tid, 4*tid+4). Per k4: 8 broadcast LDS reads
// feed 128 FMAs (16 FMA/read) -- LDS pipe no longer binding.
__global__ __launch_bounds__(256, 2) void layer2_kernel(
    const int* __restrict__ cnt, const int* __restrict__ toklist,
    const int* __restrict__ nW, const int* __restrict__ work2,
    const float* __restrict__ H,
    const float* __restrict__ W2_0, const float* __restrict__ W2_1,
    const float* __restrict__ W2_2, const float* __restrict__ W2_3,
    const float* __restrict__ b2_0, const float* __restrict__ b2_1,
    const float* __restrict__ b2_2, const float* __restrict__ b2_3,
    const float* __restrict__ te_0, const float* __restrict__ te_1,
    const float* __restrict__ te_2, const float* __restrict__ te_3,
    float* __restrict__ out)
{
    const int slot = blockIdx.x, mod = blockIdx.y;
    if (slot >= nW[1]) return;
    const int ent = work2[slot];
    const int cat = ent & 255, chunk = ent >> 8;
    const int nC = cnt[cat];
    const int start = chunk * 8;
    int nThis = nC - start;
    if (nThis > 8) nThis = 8;
    const int tid = threadIdx.x;
    const int col = 4 * tid;                       // 256 threads x 4 = 1024 cols

    __shared__ float sH[8 * 512];                  // 16 KiB, [t][k] zero-padded
    __shared__ int sTok[8];
    if (tid < 8) sTok[tid] = (tid < nThis) ? toklist[cat * NTOK + start + tid] : 0;
    __syncthreads();

    for (int idx = tid; idx < 8 * 128; idx += 256) {   // 1024 float4s
        const int t = idx >> 7, e4 = idx & 127;
        float4 v = make_float4(0.f, 0.f, 0.f, 0.f);
        if (t < nThis)
            v = ((const float4*)(H + (sTok[t] * 4 + mod) * HID))[e4];
        ((float4*)sH)[idx] = v;
    }
    __syncthreads();

    const float* W2 = (mod == 0) ? W2_0 : (mod == 1) ? W2_1 : (mod == 2) ? W2_2 : W2_3;
    const float* b2 = (mod == 0) ? b2_0 : (mod == 1) ? b2_1 : (mod == 2) ? b2_2 : b2_3;
    const float* te = (mod == 0) ? te_0 : (mod == 1) ? te_1 : (mod == 2) ? te_2 : te_3;

    const float* Wcol = W2 + cat * (HID * EMB) + col;

    float4 acc[8];
#pragma unroll
    for (int t = 0; t < 8; ++t) acc[t] = make_float4(0.f, 0.f, 0.f, 0.f);

#pragma unroll 2
    for (int k4 = 0; k4 < 128; ++k4) {
        const float* p = Wcol + (k4 * 4) * EMB;
        const float4 w0 = *(const float4*)(p);
        const float4 w1 = *(const float4*)(p + EMB);
        const float4 w2 = *(const float4*)(p + 2 * EMB);
        const float4 w3 = *(const float4*)(p + 3 * EMB);
#pragma unroll
        for (int t = 0; t < 8; ++t) {
            const float4 h4 = ((const float4*)sH)[t * 128 + k4];
            acc[t].x += h4.x * w0.x + h4.y * w1.x + h4.z * w2.x + h4.w * w3.x;
            acc[t].y += h4.x * w0.y + h4.y * w1.y + h4.z * w2.y + h4.w * w3.y;
            acc[t].z += h4.x * w0.z + h4.y * w1.z + h4.z * w2.z + h4.w * w3.z;
            acc[t].w += h4.x * w0.w + h4.y * w1.w + h4.z * w2.w + h4.w * w3.w;
        }
    }

    const float4 bb = *(const float4*)(b2 + cat * EMB + col);
    const float4 tt = *(const float4*)(te + col);
    const float4 b4 = make_float4(bb.x + tt.x, bb.y + tt.y, bb.z + tt.z, bb.w + tt.w);
#pragma unroll
    for (int t = 0; t < 8; ++t) {
        if (t >= nThis) break;
        float4 o;
        o.x = acc[t].x + b4.x;
        o.y = acc[t].y + b4.y;
        o.z = acc[t].z + b4.z;
        o.w = acc[t].w + b4.w;
        *(float4*)(out + (sTok[t] * 4 + mod) * EMB + col) = o;
    }
}

extern "C" void kernel_launch(void* const* d_in, const int* in_sizes, int n_in,
                              void* d_out, int out_size, void* d_ws, size_t ws_size,
                              hipStream_t stream) {
    const float* state = (const float*)d_in[0];
    const int*   ids   = (const int*)d_in[1];
    const float *W1[4], *b1[4], *W2[4], *b2[4], *te[4];
    for (int m = 0; m < 4; ++m) {
        W1[m] = (const float*)d_in[2 + 5 * m + 0];
        b1[m] = (const float*)d_in[2 + 5 * m + 1];
        W2[m] = (const float*)d_in[2 + 5 * m + 2];
        b2[m] = (const float*)d_in[2 + 5 * m + 3];
        te[m] = (const float*)d_in[2 + 5 * m + 4];
    }
    char* ws = (char*)d_ws;
    int*   cnt     = (int*)ws;
    int*   nW      = (int*)(ws + 128);
    int*   work1   = (int*)(ws + 256);
    int*   work2   = (int*)(ws + 640);
    int*   toklist = (int*)(ws + 1024);
    float* H       = (float*)(ws + 66560);
    float* out     = (float*)d_out;

    bucket_kernel<<<1, 512, 0, stream>>>(ids, cnt, nW, work1, work2, toklist);
    layer1_kernel<<<dim3(96, 4), 128, 0, stream>>>(
        state, cnt, toklist, nW, work1,
        W1[0], W1[1], W1[2], W1[3],
        b1[0], b1[1], b1[2], b1[3], H);
    layer2_kernel<<<dim3(96, 4), 256, 0, stream>>>(
        cnt, toklist, nW, work2, H,
        W2[0], W2[1], W2[2], W2[3],
        b2[0], b2[1], b2[2], b2[3],
        te[0], te[1], te[2], te[3], out);
}